// Round 10
// baseline (181.480 us; speedup 1.0000x reference)
//
#include <hip/hip_runtime.h>
#include <hip/hip_bf16.h>

#define DIM 2048
#define NB  64
#define KSL 4          // K-split slices for qkv GEMM (512 k per block, 2 chunks)

typedef short bf16x8 __attribute__((ext_vector_type(8)));
typedef short s16x4  __attribute__((ext_vector_type(4)));
typedef float f32x4  __attribute__((ext_vector_type(4)));

__device__ __forceinline__ unsigned short f32_to_bf16_rne(float f) {
  unsigned u = __builtin_bit_cast(unsigned, f);
  unsigned r = u + 0x7FFF + ((u >> 16) & 1);
  return (unsigned short)(r >> 16);
}

// 4 floats -> 4 bf16 (rne) packed as s16x4 (integer pack; trivially copyable)
__device__ __forceinline__ s16x4 pk_bf16_4(float a, float b, float c, float d) {
  s16x4 r;
  r[0] = (short)f32_to_bf16_rne(a);
  r[1] = (short)f32_to_bf16_rne(b);
  r[2] = (short)f32_to_bf16_rne(c);
  r[3] = (short)f32_to_bf16_rne(d);
  return r;
}

// x -> hi/lo bf16 in MFMA-fragment order + zero the dense qkv accumulator
// (ws poisoned 0xAA each launch; qkv_mfma atomically accumulates into qkv).
__global__ __launch_bounds__(256)
void prep(const float* __restrict__ x, unsigned short* __restrict__ xrh,
          unsigned short* __restrict__ xrl, float* __restrict__ qkv) {
  const int tg = blockIdx.x * 256 + threadIdx.x;   // [0, 32768)
#pragma unroll
  for (int z = 0; z < 3; ++z)
    *(float4*)(qkv + ((size_t)z * 32768 + tg) * 4) = make_float4(0.f,0.f,0.f,0.f);

  const int b = tg >> 9;
  const int k = (tg & 511) * 4;
  float4 f = *(const float4*)(x + (size_t)b * DIM + k);
  const int mt = b >> 4, l15 = b & 15;
  const int ck = k >> 5, quad = (k >> 3) & 3, u = k & 7;
  const size_t off = (((size_t)(mt * 64 + ck) * 64) + quad * 16 + l15) * 8 + u;
  float vf[4] = {f.x, f.y, f.z, f.w};
  ushort4 h4, l4;
  unsigned short* hp = &h4.x;
  unsigned short* lp = &l4.x;
#pragma unroll
  for (int e = 0; e < 4; ++e) {
    unsigned short h = f32_to_bf16_rne(vf[e]);
    float hf = __builtin_bit_cast(float, ((unsigned)h) << 16);
    hp[e] = h;
    lp[e] = f32_to_bf16_rne(vf[e] - hf);
  }
  *(ushort4*)(xrh + off) = h4;
  *(ushort4*)(xrl + off) = l4;
}

#define WSTR 260   // LDS row stride (shorts): 130 dwords == 2 mod 32 -> 4-way max

__device__ __forceinline__ void conv_store_w(short (*wh)[WSTR], short (*wl)[WSTR],
                                             const float4* wreg, int wave, int lane) {
#pragma unroll
  for (int p = 0; p < 8; ++p) {
    const int r = p * 4 + wave;
    float wf[4] = {wreg[p].x, wreg[p].y, wreg[p].z, wreg[p].w};
    s16x4 h4, l4;
#pragma unroll
    for (int e = 0; e < 4; ++e) {
      unsigned uu = __builtin_bit_cast(unsigned, wf[e]);
      h4[e] = (short)(uu >> 16);                              // trunc hi
      float hf = __builtin_bit_cast(float, uu & 0xFFFF0000u);
      float res = wf[e] - hf;
      l4[e] = (short)(__builtin_bit_cast(unsigned, res) >> 16);  // trunc lo
    }
    *(s16x4*)&wh[r][lane * 4] = h4;
    *(s16x4*)&wl[r][lane * 4] = l4;
  }
}

// C[b][j] = sum_k x[b][k]*W[j][k].  MFMA 16x16x32 bf16, 3-term hi/lo split.
// Grid (64, KSL, 3); 512 k per block, chunk-1 W register-prefetched over
// chunk-0 compute.  Epilogue: atomicAdd into dense qkv[mat][b][j].
__global__ __launch_bounds__(256)
void qkv_mfma(const unsigned short* __restrict__ xrh,
              const unsigned short* __restrict__ xrl,
              const float* __restrict__ Wq, const float* __restrict__ Wk,
              const float* __restrict__ Wv, float* __restrict__ qkv) {
  const int mat = blockIdx.z;
  const float* __restrict__ W = (mat == 0) ? Wq : ((mat == 1) ? Wk : Wv);
  const int t = threadIdx.x;
  const int wave = t >> 6, lane = t & 63;
  const int l15 = lane & 15, quad = lane >> 4;
  const int j0 = blockIdx.x * 32;
  const int kb0 = blockIdx.y * 512;

  __shared__ __align__(16) short wh[32][WSTR];
  __shared__ __align__(16) short wl[32][WSTR];

  const int jh = wave & 1;
  const int mh = wave >> 1;
  const int frow = jh * 16 + l15;
  f32x4 acc[2] = {{0.f,0.f,0.f,0.f},{0.f,0.f,0.f,0.f}};

  float4 wa[8], wb[8];
#pragma unroll
  for (int p = 0; p < 8; ++p)
    wa[p] = *(const float4*)(W + (size_t)(j0 + p * 4 + wave) * DIM + kb0 + lane * 4);

#pragma unroll
  for (int c = 0; c < 2; ++c) {
    if (c == 0) conv_store_w(wh, wl, wa, wave, lane);
    else        conv_store_w(wh, wl, wb, wave, lane);
    if (c == 0) {
#pragma unroll
      for (int p = 0; p < 8; ++p)
        wb[p] = *(const float4*)(W + (size_t)(j0 + p * 4 + wave) * DIM +
                                 kb0 + 256 + lane * 4);   // in flight over compute
    }
    __syncthreads();

    const int ckb = blockIdx.y * 16 + c * 8;
#pragma unroll
    for (int kk = 0; kk < 8; ++kk) {
      bf16x8 whf, wlf;
      *(s16x4*)&whf       = *(const s16x4*)&wh[frow][kk * 32 + quad * 8];
      *(((s16x4*)&whf)+1) = *(const s16x4*)&wh[frow][kk * 32 + quad * 8 + 4];
      *(s16x4*)&wlf       = *(const s16x4*)&wl[frow][kk * 32 + quad * 8];
      *(((s16x4*)&wlf)+1) = *(const s16x4*)&wl[frow][kk * 32 + quad * 8 + 4];
      const int ck = ckb + kk;
#pragma unroll
      for (int u = 0; u < 2; ++u) {
        const int mt = mh * 2 + u;
        const size_t xo = (((size_t)(mt * 64 + ck)) * 64 + lane) * 8;
        bf16x8 ah = *(const bf16x8*)(xrh + xo);
        bf16x8 al = *(const bf16x8*)(xrl + xo);
        acc[u] = __builtin_amdgcn_mfma_f32_16x16x32_bf16(ah, whf, acc[u], 0, 0, 0);
        acc[u] = __builtin_amdgcn_mfma_f32_16x16x32_bf16(al, whf, acc[u], 0, 0, 0);
        acc[u] = __builtin_amdgcn_mfma_f32_16x16x32_bf16(ah, wlf, acc[u], 0, 0, 0);
      }
    }
    if (c == 0) __syncthreads();
  }

  float* __restrict__ pb = qkv + (size_t)mat * NB * DIM + j0 + jh * 16 + l15;
#pragma unroll
  for (int u = 0; u < 2; ++u)
#pragma unroll
    for (int r = 0; r < 4; ++r) {
      const int b = (mh * 2 + u) * 16 + quad * 4 + r;
      atomicAdd(pb + (size_t)b * DIM, acc[u][r]);
    }
}

// Attention via MFMA j-reduction.  Wave = one (b, 16-i tile); per 32-j step
// each lane computes 8 exps DIRECTLY into an A-fragment (m=l15 i-row,
// k=quad*8+u j-col -- layout verified by prep/qkv all session), B-fragment
// column n=0 = bf16(v_j), n=1 = 1.0, else 0 (B layout verified by qkv's W
// fragments).  One MFMA accumulates D[i,0]=num, D[i,1]=den: the per-j
// add/fmac and all load redundancy of R5-R8 collapse onto the MFMA pipe,
// leaving the trans pipe as the only load (floor ~14 us).
// NO max subtraction (|c*k| <= ~29, fp32/bf16-safe; validated R4-R8).
__global__ __launch_bounds__(256)
void attn_mfma(const float* __restrict__ qkv, float* __restrict__ out) {
  const int b = blockIdx.y;
  const int wave = threadIdx.x >> 6, lane = threadIdx.x & 63;
  const int l15 = lane & 15, quad = lane >> 4;
  const int it = blockIdx.x * 4 + wave;            // i-tile [0,128)
  const float* __restrict__ kp = qkv + (size_t)(NB + b) * DIM;
  const float* __restrict__ vp = qkv + (size_t)(2 * NB + b) * DIM;
  const float c = qkv[(size_t)b * DIM + it * 16 + l15] * 1.4426950408889634f;

  // constant B columns for this lane (n = l15): 1.0 at n==1, 0 elsewhere;
  // n==0 gets v per step.
  const short one_bf = (short)0x3F80;
  s16x4 cfrag = {0, 0, 0, 0};
  if (l15 == 1) { cfrag[0] = one_bf; cfrag[1] = one_bf; cfrag[2] = one_bf; cfrag[3] = one_bf; }
  const bool isv = (l15 == 0);

  f32x4 acc = {0.f, 0.f, 0.f, 0.f};
#pragma unroll 2
  for (int j0 = 0; j0 < DIM; j0 += 32) {
    const int jb = j0 + quad * 8;
    float4 k0 = *(const float4*)(kp + jb);
    float4 k1 = *(const float4*)(kp + jb + 4);
    float4 v0 = *(const float4*)(vp + jb);
    float4 v1 = *(const float4*)(vp + jb + 4);
    float e0 = __builtin_amdgcn_exp2f(c * k0.x);
    float e1 = __builtin_amdgcn_exp2f(c * k0.y);
    float e2 = __builtin_amdgcn_exp2f(c * k0.z);
    float e3 = __builtin_amdgcn_exp2f(c * k0.w);
    float e4 = __builtin_amdgcn_exp2f(c * k1.x);
    float e5 = __builtin_amdgcn_exp2f(c * k1.y);
    float e6 = __builtin_amdgcn_exp2f(c * k1.z);
    float e7 = __builtin_amdgcn_exp2f(c * k1.w);
    bf16x8 efrag;
    *(s16x4*)&efrag         = pk_bf16_4(e0, e1, e2, e3);
    *(((s16x4*)&efrag) + 1) = pk_bf16_4(e4, e5, e6, e7);
    s16x4 vlo = pk_bf16_4(v0.x, v0.y, v0.z, v0.w);
    s16x4 vhi = pk_bf16_4(v1.x, v1.y, v1.z, v1.w);
    bf16x8 bfrag;
    *(s16x4*)&bfrag         = isv ? vlo : cfrag;
    *(((s16x4*)&bfrag) + 1) = isv ? vhi : cfrag;
    acc = __builtin_amdgcn_mfma_f32_16x16x32_bf16(efrag, bfrag, acc, 0, 0, 0);
  }

  // D: col=l15 (0=num, 1=den), row i = it*16 + quad*4 + r.
  float d0 = __shfl_xor(acc[0], 1);
  float d1 = __shfl_xor(acc[1], 1);
  float d2 = __shfl_xor(acc[2], 1);
  float d3 = __shfl_xor(acc[3], 1);
  if (l15 == 0) {
    float* __restrict__ ob = out + (size_t)b * DIM + it * 16 + quad * 4;
    ob[0] = acc[0] / d0;
    ob[1] = acc[1] / d1;
    ob[2] = acc[2] / d2;
    ob[3] = acc[3] / d3;
  }
}

extern "C" void kernel_launch(void* const* d_in, const int* in_sizes, int n_in,
                              void* d_out, int out_size, void* d_ws, size_t ws_size,
                              hipStream_t stream) {
  const float* x  = (const float*)d_in[0];
  const float* Wq = (const float*)d_in[1];
  const float* Wk = (const float*)d_in[2];
  const float* Wv = (const float*)d_in[3];
  float* out = (float*)d_out;

  char* w = (char*)d_ws;
  unsigned short* xrh = (unsigned short*)w;                  // 256 KB
  unsigned short* xrl = (unsigned short*)(w + (512 << 10));  // 256 KB
  float* qkv = (float*)(w + (1 << 20));                      // 1.57 MB dense

  hipLaunchKernelGGL(prep, dim3(128), dim3(256), 0, stream, x, xrh, xrl, qkv);
  hipLaunchKernelGGL(qkv_mfma, dim3(64, KSL, 3), dim3(256), 0, stream,
                     xrh, xrl, Wq, Wk, Wv, qkv);
  hipLaunchKernelGGL(attn_mfma, dim3(32, NB), dim3(256), 0, stream, qkv, out);
}

// Round 11
// 132.704 us; speedup vs baseline: 1.3675x; 1.3675x over previous
//
#include <hip/hip_runtime.h>
#include <hip/hip_bf16.h>

#define DIM 2048
#define NB  64
#define KSL 4          // K-split slices for qkv GEMM (512 k per block, 2 chunks)
#define JSL 8          // j-split slices for attention (256-j slices)

typedef short bf16x8 __attribute__((ext_vector_type(8)));
typedef short s16x4  __attribute__((ext_vector_type(4)));
typedef float f32x4  __attribute__((ext_vector_type(4)));
typedef float f32x2  __attribute__((ext_vector_type(2)));

__device__ __forceinline__ unsigned short f32_to_bf16_rne(float f) {
  unsigned u = __builtin_bit_cast(unsigned, f);
  unsigned r = u + 0x7FFF + ((u >> 16) & 1);
  return (unsigned short)(r >> 16);
}

// x -> hi/lo bf16 in MFMA-fragment order (coalesced A loads in qkv_mfma)
__global__ __launch_bounds__(256)
void prep(const float* __restrict__ x, unsigned short* __restrict__ xrh,
          unsigned short* __restrict__ xrl) {
  const int tg = blockIdx.x * 256 + threadIdx.x;   // [0, 32768)
  const int b = tg >> 9;
  const int k = (tg & 511) * 4;
  float4 f = *(const float4*)(x + (size_t)b * DIM + k);
  const int mt = b >> 4, l15 = b & 15;
  const int ck = k >> 5, quad = (k >> 3) & 3, u = k & 7;
  const size_t off = (((size_t)(mt * 64 + ck) * 64) + quad * 16 + l15) * 8 + u;
  float vf[4] = {f.x, f.y, f.z, f.w};
  ushort4 h4, l4;
  unsigned short* hp = &h4.x;
  unsigned short* lp = &l4.x;
#pragma unroll
  for (int e = 0; e < 4; ++e) {
    unsigned short h = f32_to_bf16_rne(vf[e]);
    float hf = __builtin_bit_cast(float, ((unsigned)h) << 16);
    hp[e] = h;
    lp[e] = f32_to_bf16_rne(vf[e] - hf);
  }
  *(ushort4*)(xrh + off) = h4;
  *(ushort4*)(xrl + off) = l4;
}

#define WSTR 260   // LDS row stride (shorts): 130 dwords == 2 mod 32 -> 4-way max

__device__ __forceinline__ void conv_store_w(short (*wh)[WSTR], short (*wl)[WSTR],
                                             const float4* wreg, int wave, int lane) {
#pragma unroll
  for (int p = 0; p < 8; ++p) {
    const int r = p * 4 + wave;
    float wf[4] = {wreg[p].x, wreg[p].y, wreg[p].z, wreg[p].w};
    s16x4 h4, l4;
#pragma unroll
    for (int e = 0; e < 4; ++e) {
      unsigned uu = __builtin_bit_cast(unsigned, wf[e]);
      h4[e] = (short)(uu >> 16);                              // trunc hi
      float hf = __builtin_bit_cast(float, uu & 0xFFFF0000u);
      float res = wf[e] - hf;
      l4[e] = (short)(__builtin_bit_cast(unsigned, res) >> 16);  // trunc lo
    }
    *(s16x4*)&wh[r][lane * 4] = h4;
    *(s16x4*)&wl[r][lane * 4] = l4;
  }
}

// C[b][j] = sum_k x[b][k]*W[j][k].  MFMA 16x16x32 bf16, 3-term hi/lo split.
// Grid (64, KSL, 3); 512 k per block, chunk-1 W register-prefetched over
// chunk-0 compute.  Writes per-slice partials part[sl][mat][b][j].
__global__ __launch_bounds__(256)
void qkv_mfma(const unsigned short* __restrict__ xrh,
              const unsigned short* __restrict__ xrl,
              const float* __restrict__ Wq, const float* __restrict__ Wk,
              const float* __restrict__ Wv, float* __restrict__ part) {
  const int mat = blockIdx.z;
  const float* __restrict__ W = (mat == 0) ? Wq : ((mat == 1) ? Wk : Wv);
  const int t = threadIdx.x;
  const int wave = t >> 6, lane = t & 63;
  const int l15 = lane & 15, quad = lane >> 4;
  const int j0 = blockIdx.x * 32;
  const int kb0 = blockIdx.y * 512;

  __shared__ __align__(16) short wh[32][WSTR];
  __shared__ __align__(16) short wl[32][WSTR];

  const int jh = wave & 1;
  const int mh = wave >> 1;
  const int frow = jh * 16 + l15;
  f32x4 acc[2] = {{0.f,0.f,0.f,0.f},{0.f,0.f,0.f,0.f}};

  float4 wa[8], wb[8];
#pragma unroll
  for (int p = 0; p < 8; ++p)
    wa[p] = *(const float4*)(W + (size_t)(j0 + p * 4 + wave) * DIM + kb0 + lane * 4);

#pragma unroll
  for (int c = 0; c < 2; ++c) {
    if (c == 0) conv_store_w(wh, wl, wa, wave, lane);
    else        conv_store_w(wh, wl, wb, wave, lane);
    if (c == 0) {
#pragma unroll
      for (int p = 0; p < 8; ++p)
        wb[p] = *(const float4*)(W + (size_t)(j0 + p * 4 + wave) * DIM +
                                 kb0 + 256 + lane * 4);   // in flight over compute
    }
    __syncthreads();

    const int ckb = blockIdx.y * 16 + c * 8;
#pragma unroll
    for (int kk = 0; kk < 8; ++kk) {
      bf16x8 whf, wlf;
      *(s16x4*)&whf       = *(const s16x4*)&wh[frow][kk * 32 + quad * 8];
      *(((s16x4*)&whf)+1) = *(const s16x4*)&wh[frow][kk * 32 + quad * 8 + 4];
      *(s16x4*)&wlf       = *(const s16x4*)&wl[frow][kk * 32 + quad * 8];
      *(((s16x4*)&wlf)+1) = *(const s16x4*)&wl[frow][kk * 32 + quad * 8 + 4];
      const int ck = ckb + kk;
#pragma unroll
      for (int u = 0; u < 2; ++u) {
        const int mt = mh * 2 + u;
        const size_t xo = (((size_t)(mt * 64 + ck)) * 64 + lane) * 8;
        bf16x8 ah = *(const bf16x8*)(xrh + xo);
        bf16x8 al = *(const bf16x8*)(xrl + xo);
        acc[u] = __builtin_amdgcn_mfma_f32_16x16x32_bf16(ah, whf, acc[u], 0, 0, 0);
        acc[u] = __builtin_amdgcn_mfma_f32_16x16x32_bf16(al, whf, acc[u], 0, 0, 0);
        acc[u] = __builtin_amdgcn_mfma_f32_16x16x32_bf16(ah, wlf, acc[u], 0, 0, 0);
      }
    }
    if (c == 0) __syncthreads();
  }

  // D layout (verified R2-R10): col(j)=lane&15, row(b)=quad*4+reg
  float* __restrict__ pb =
      part + ((size_t)(blockIdx.y * 3 + mat) * NB) * DIM + j0 + jh * 16 + l15;
#pragma unroll
  for (int u = 0; u < 2; ++u)
#pragma unroll
    for (int r = 0; r < 4; ++r) {
      const int b = (mh * 2 + u) * 16 + quad * 4 + r;
      pb[(size_t)b * DIM] = acc[u][r];
    }
}

// out[b][i] partials over a 256-j slice; K-slice reduction of q,k,v folded in.
// TWO i-values per thread: each LDS k/v read feeds two exp-chains, so the
// main pipe (48 ops/8j) stays under the trans pipe (16 exp = 128 cyc/8j)
// -- trans-bound by construction.  Grid (4, JSL, 64) = 2048 blocks ->
// 32 waves/CU hides ds_read/global latency (R5/R8 lesson).
// NO max subtraction (|c*k| <~ 29, fp32-safe; validated R4-R8).
__global__ __launch_bounds__(256)
void attn(const float* __restrict__ part, f32x2* __restrict__ pnd) {
  const int b = blockIdx.z, js = blockIdx.y, t = threadIdx.x;
  const int i0 = blockIdx.x * 512;                 // 512 i per block, 2/thread
  const int ia = i0 + t, ib = i0 + 256 + t;
  const int jb = js * (DIM / JSL);                 // 256-j slice

  __shared__ __align__(16) float ks[DIM / JSL];
  __shared__ __align__(16) float vs[DIM / JSL];

  // stage k,v slice (thread t <-> j = jb + t), reducing over K-slices
  float kv = 0.f, vv = 0.f, qa = 0.f, qb = 0.f;
#pragma unroll
  for (int sl = 0; sl < KSL; ++sl) {
    kv += part[((size_t)(sl * 3 + 1) * NB + b) * DIM + jb + t];
    vv += part[((size_t)(sl * 3 + 2) * NB + b) * DIM + jb + t];
    qa += part[((size_t)(sl * 3 + 0) * NB + b) * DIM + ia];
    qb += part[((size_t)(sl * 3 + 0) * NB + b) * DIM + ib];
  }
  ks[t] = kv;
  vs[t] = vv;
  __syncthreads();

  const float ca = qa * 1.4426950408889634f;
  const float cb = qb * 1.4426950408889634f;
  float na0=0.f, na1=0.f, da0=0.f, da1=0.f;
  float nb0=0.f, nb1=0.f, db0=0.f, db1=0.f;
#pragma unroll 4
  for (int j = 0; j < DIM / JSL; j += 8) {
    float4 k0 = *(const float4*)(ks + j);        // uniform addr: LDS broadcast
    float4 k1 = *(const float4*)(ks + j + 4);
    float4 v0 = *(const float4*)(vs + j);
    float4 v1 = *(const float4*)(vs + j + 4);
    float kf[8] = {k0.x,k0.y,k0.z,k0.w,k1.x,k1.y,k1.z,k1.w};
    float vf[8] = {v0.x,v0.y,v0.z,v0.w,v1.x,v1.y,v1.z,v1.w};
#pragma unroll
    for (int u = 0; u < 8; ++u) {
      float ea = __builtin_amdgcn_exp2f(ca * kf[u]);
      float eb = __builtin_amdgcn_exp2f(cb * kf[u]);
      if (u & 1) {
        da1 += ea; na1 = fmaf(ea, vf[u], na1);
        db1 += eb; nb1 = fmaf(eb, vf[u], nb1);
      } else {
        da0 += ea; na0 = fmaf(ea, vf[u], na0);
        db0 += eb; nb0 = fmaf(eb, vf[u], nb0);
      }
    }
  }
  f32x2 nda, ndb;
  nda.x = na0 + na1; nda.y = da0 + da1;
  ndb.x = nb0 + nb1; ndb.y = db0 + db1;
  pnd[((size_t)b * JSL + js) * DIM + ia] = nda;
  pnd[((size_t)b * JSL + js) * DIM + ib] = ndb;
}

__global__ __launch_bounds__(256)
void attn_fin(const f32x2* __restrict__ pnd, float* __restrict__ out) {
  const int b = blockIdx.y;
  const int i = blockIdx.x * 256 + threadIdx.x;
  float n = 0.f, d = 0.f;
#pragma unroll
  for (int s = 0; s < JSL; ++s) {
    f32x2 p = pnd[((size_t)b * JSL + s) * DIM + i];
    n += p.x; d += p.y;
  }
  out[(size_t)b * DIM + i] = n / d;
}

extern "C" void kernel_launch(void* const* d_in, const int* in_sizes, int n_in,
                              void* d_out, int out_size, void* d_ws, size_t ws_size,
                              hipStream_t stream) {
  const float* x  = (const float*)d_in[0];
  const float* Wq = (const float*)d_in[1];
  const float* Wk = (const float*)d_in[2];
  const float* Wv = (const float*)d_in[3];
  float* out = (float*)d_out;

  char* w = (char*)d_ws;
  unsigned short* xrh = (unsigned short*)w;                  // 256 KB
  unsigned short* xrl = (unsigned short*)(w + (512 << 10));  // 256 KB
  float* part = (float*)(w + (1 << 20));                     // 6.3 MB (KSL=4)
  f32x2* pnd  = (f32x2*)(w + (16 << 20));                    // 8 MB (JSL=8)

  hipLaunchKernelGGL(prep, dim3(128), dim3(256), 0, stream, x, xrh, xrl);
  hipLaunchKernelGGL(qkv_mfma, dim3(64, KSL, 3), dim3(256), 0, stream,
                     xrh, xrl, Wq, Wk, Wv, part);
  hipLaunchKernelGGL(attn, dim3(4, JSL, NB), dim3(256), 0, stream, part, pnd);
  hipLaunchKernelGGL(attn_fin, dim3(8, NB), dim3(256), 0, stream, pnd, out);
}